// Round 3
// baseline (3445.898 us; speedup 1.0000x reference)
//
#include <hip/hip_runtime.h>
#include <hip/hip_bf16.h>
#include <math.h>

// EnhancedResGCN forward, fp32 baseline.
// N=100000, E=1600000, IN=128, H=64, C=16, L=4.
// Key identity: graph_conv(h) = (D_in^-1/2 A^T D_out^-1/2 h) W = S (h W):
// apply W (and out_norm row-scale) BEFORE the edge scatter -> all SpMMs 64-wide.

#define EPS_BN 1e-5f

static inline int cdiv_i(int a, int b){ return (a + b - 1) / b; }

// ---------------- degree / norm ----------------
__global__ void k_deg(const int* __restrict__ src, const int* __restrict__ dst,
                      float* __restrict__ outd, float* __restrict__ ind, int E){
  int e = blockIdx.x * blockDim.x + threadIdx.x;
  if (e < E){
    atomicAdd(&outd[src[e]], 1.f);
    atomicAdd(&ind[dst[e]], 1.f);
  }
}

__global__ void k_norm(float* __restrict__ outn, float* __restrict__ inn,
                       float* __restrict__ invind, int n){
  int i = blockIdx.x * blockDim.x + threadIdx.x;
  if (i < n){
    float od = fmaxf(outn[i], 1.f);
    float id = fmaxf(inn[i], 1.f);
    outn[i]   = rsqrtf(od);   // out_norm
    inn[i]    = rsqrtf(id);   // in_norm
    invind[i] = 1.f / id;     // 1/in_deg (clamped)
  }
}

// ---------------- dense GEMM: Y[n,nout] = (RS? X*rscale : X)[n,K] @ W[K,nout] (+bias)(+=Y)(relu) ----
// 64x64 block tile, 256 threads, 4x4 register tile per thread, K chunked by 32.
template<int K, int RELU, int ACC, int RS>
__global__ __launch_bounds__(256) void k_gemm(
    const float* __restrict__ X, const float* __restrict__ W,
    const float* __restrict__ bias, const float* __restrict__ rscale,
    float* __restrict__ Y, int n, int nout)
{
  __shared__ __align__(16) float XT[32][68];  // [k][row], pad 68 keeps 16B align + banks spread
  __shared__ __align__(16) float WS[32][64];  // [k][col]
  const int tid = threadIdx.x;
  const int tx = tid & 15, ty = tid >> 4;
  const int row0 = blockIdx.x * 64, col0 = blockIdx.y * 64;
  float acc[4][4] = {};
  for (int k0 = 0; k0 < K; k0 += 32){
    __syncthreads();
#pragma unroll
    for (int it = 0; it < 8; ++it){           // stage X chunk (64 rows x 32 k), transposed
      int idx = it * 256 + tid;
      int r = idx >> 5, kk = idx & 31;
      int row = row0 + r;
      float v = 0.f;
      if (row < n){
        v = X[(size_t)row * K + (k0 + kk)];
        if (RS) v *= rscale[row];
      }
      XT[kk][r] = v;
    }
#pragma unroll
    for (int it = 0; it < 8; ++it){           // stage W chunk (32 k x 64 cols)
      int idx = it * 256 + tid;
      int kk = idx >> 6, c = idx & 63;
      int col = col0 + c;
      WS[kk][c] = (col < nout) ? W[(size_t)(k0 + kk) * nout + col] : 0.f;
    }
    __syncthreads();
#pragma unroll
    for (int kk = 0; kk < 32; ++kk){
      const float4 xv = *reinterpret_cast<const float4*>(&XT[kk][ty * 4]);
      const float4 wv = *reinterpret_cast<const float4*>(&WS[kk][tx * 4]);
      float xa[4] = {xv.x, xv.y, xv.z, xv.w};
      float wa[4] = {wv.x, wv.y, wv.z, wv.w};
#pragma unroll
      for (int i = 0; i < 4; ++i)
#pragma unroll
        for (int j = 0; j < 4; ++j)
          acc[i][j] = fmaf(xa[i], wa[j], acc[i][j]);
    }
  }
#pragma unroll
  for (int i = 0; i < 4; ++i){
    int row = row0 + ty * 4 + i;
    if (row >= n) continue;
#pragma unroll
    for (int j = 0; j < 4; ++j){
      int col = col0 + tx * 4 + j;
      if (col >= nout) continue;
      float v = acc[i][j];
      if (bias) v += bias[col];
      size_t o = (size_t)row * nout + col;
      if (ACC) v += Y[o];
      if (RELU) v = fmaxf(v, 0.f);
      Y[o] = v;
    }
  }
}

// ---------------- SpMM scatter: out[dst] += x[src], 64-wide rows, wave per edge ----------------
__global__ void k_spmm(const float* __restrict__ x, const int* __restrict__ src,
                       const int* __restrict__ dst, float* __restrict__ out, int E){
  int e = blockIdx.x * 4 + (threadIdx.x >> 6);
  int f = threadIdx.x & 63;
  if (e < E){
    int s = src[e], d = dst[e];
    atomicAdd(&out[(size_t)d * 64 + f], x[(size_t)s * 64 + f]);
  }
}

// ---------------- BatchNorm stats over z = agg*in_norm + b ----------------
__global__ void k_bnstats(const float* __restrict__ agg, const float* __restrict__ innorm,
                          const float* __restrict__ b, float* __restrict__ sum,
                          float* __restrict__ sumsq, int n){
  __shared__ float s1[4][64], s2[4][64];
  int f = threadIdx.x & 63, g = threadIdx.x >> 6;
  float bf = b[f];
  float a1 = 0.f, a2 = 0.f;
  for (int row = blockIdx.x * 4 + g; row < n; row += gridDim.x * 4){
    float z = agg[(size_t)row * 64 + f] * innorm[row] + bf;
    a1 += z; a2 += z * z;
  }
  s1[g][f] = a1; s2[g][f] = a2;
  __syncthreads();
  if (threadIdx.x < 64){
    float t1 = s1[0][f] + s1[1][f] + s1[2][f] + s1[3][f];
    float t2 = s2[0][f] + s2[1][f] + s2[2][f] + s2[3][f];
    atomicAdd(&sum[f], t1);
    atomicAdd(&sumsq[f], t2);
  }
}

__global__ void k_bnfin(const float* __restrict__ sum, const float* __restrict__ sumsq,
                        const float* __restrict__ gamma, const float* __restrict__ beta,
                        float* __restrict__ scale, float* __restrict__ shift, float inv_n){
  int f = threadIdx.x;  // 64 threads
  float mu  = sum[f] * inv_n;
  float var = sumsq[f] * inv_n - mu * mu;
  float sc  = gamma[f] * rsqrtf(var + EPS_BN);
  scale[f] = sc;
  shift[f] = beta[f] - mu * sc;
}

// ---------------- epilogue: h = relu(BN(agg*innorm+b) [+ hres]) ----------------
__global__ void k_post(const float* __restrict__ agg, const float* __restrict__ innorm,
                       const float* __restrict__ b, const float* __restrict__ scale,
                       const float* __restrict__ shift, const float* __restrict__ hres,
                       float* __restrict__ hout, int n64){
  int i = blockIdx.x * blockDim.x + threadIdx.x;
  if (i >= n64) return;
  int f = i & 63, row = i >> 6;
  float z = agg[i] * innorm[row] + b[f];
  z = z * scale[f] + shift[f];
  if (hres) z += hres[i];
  hout[i] = fmaxf(z, 0.f);
}

// ---------------- attention: a = sigmoid(v . W2 + b2); h += a * nb * invind ----------------
__global__ void k_attupd(const float* __restrict__ v, const float* __restrict__ W2,
                         const float* __restrict__ b2, const float* __restrict__ nb,
                         const float* __restrict__ invind, float* __restrict__ h, int n){
  int row = blockIdx.x * 4 + (threadIdx.x >> 6);
  int f = threadIdx.x & 63;
  if (row >= n) return;
  float s = v[(size_t)row * 64 + f] * W2[f];
#pragma unroll
  for (int off = 32; off; off >>= 1) s += __shfl_xor(s, off);
  float a = 1.f / (1.f + expf(-(s + b2[0])));
  size_t o = (size_t)row * 64 + f;
  float nbm = nb[o] * invind[row];
  h[o] += a * nbm;
}

extern "C" void kernel_launch(void* const* d_in, const int* in_sizes, int n_in,
                              void* d_out, int out_size, void* d_ws, size_t ws_size,
                              hipStream_t stream) {
  const float* features = (const float*)d_in[0];
  const int*   src      = (const int*)d_in[1];
  const int*   dst      = (const int*)d_in[2];
  const float* encW1 = (const float*)d_in[3];  const float* encb1 = (const float*)d_in[4];
  const float* encW2 = (const float*)d_in[5];  const float* encb2 = (const float*)d_in[6];
  const float* encW3 = (const float*)d_in[7];  const float* encb3 = (const float*)d_in[8];
  const float* attW1 = (const float*)d_in[9];  const float* attb1 = (const float*)d_in[10];
  const float* attW2 = (const float*)d_in[11]; const float* attb2 = (const float*)d_in[12];
  const float* W0    = (const float*)d_in[13]; const float* b0    = (const float*)d_in[14];
  const float* Wrest = (const float*)d_in[15]; const float* brest = (const float*)d_in[16];
  const float* gamma = (const float*)d_in[17]; const float* beta  = (const float*)d_in[18];
  const float* fcW   = (const float*)d_in[19]; const float* fcb   = (const float*)d_in[20];
  float* out = (float*)d_out;

  const int n = in_sizes[0] / 128;   // 100000
  const int E = in_sizes[1];         // 1600000

  // workspace layout (fp32): h128[N*128] (reused as agg[N*64] and v[N*64] later),
  // hbuf[N*64] (h), nbhw[N*64] (nb / hw), norms 3N, BN scratch 256.
  float* ws      = (float*)d_ws;
  float* h128    = ws;
  float* agg     = h128;                       // alias: h128 dead after layer-0 GEMM
  float* vbuf    = h128;                       // alias: free whenever agg not live
  float* hbuf    = h128 + (size_t)n * 128;
  float* nbhw    = hbuf + (size_t)n * 64;
  float* outnorm = nbhw + (size_t)n * 64;
  float* innorm  = outnorm + n;
  float* invind  = innorm + n;
  float* bnsum   = invind + n;
  float* bnsq    = bnsum + 64;
  float* bnscale = bnsq + 64;
  float* bnshift = bnscale + 64;

  const int nt = cdiv_i(n, 64);                // 1563 row tiles
  const int spmmBlocks = cdiv_i(E, 4);

  // ---- degrees & norms ----
  hipMemsetAsync(outnorm, 0, 2 * (size_t)n * sizeof(float), stream);
  k_deg<<<cdiv_i(E, 256), 256, 0, stream>>>(src, dst, outnorm, innorm, E);
  k_norm<<<cdiv_i(n, 256), 256, 0, stream>>>(outnorm, innorm, invind, n);

  // ---- encoder MLP ----
  k_gemm<128,1,0,0><<<dim3(nt,1), 256, 0, stream>>>(features, encW1, encb1, nullptr, hbuf, n, 64);
  k_gemm<64, 1,0,0><<<dim3(nt,1), 256, 0, stream>>>(hbuf, encW2, encb2, nullptr, nbhw, n, 32);
  k_gemm<32, 0,0,0><<<dim3(nt,2), 256, 0, stream>>>(nbhw, encW3, encb3, nullptr, h128, n, 128);

  // ---- layer 0: conv on h128 ----
  k_gemm<128,0,0,1><<<dim3(nt,1), 256, 0, stream>>>(h128, W0, nullptr, outnorm, nbhw, n, 64);
  hipMemsetAsync(agg, 0, (size_t)n * 64 * sizeof(float), stream);
  k_spmm<<<spmmBlocks, 256, 0, stream>>>(nbhw, src, dst, agg, E);
  hipMemsetAsync(bnsum, 0, 128 * sizeof(float), stream);
  k_bnstats<<<512, 256, 0, stream>>>(agg, innorm, b0, bnsum, bnsq, n);
  k_bnfin<<<1, 64, 0, stream>>>(bnsum, bnsq, gamma, beta, bnscale, bnshift, 1.f / (float)n);
  k_post<<<cdiv_i(n * 64, 256), 256, 0, stream>>>(agg, innorm, b0, bnscale, bnshift, nullptr, hbuf, n * 64);

  // ---- layers 1..3 ----
  for (int i = 1; i < 4; ++i){
    const float* Wi = Wrest + (size_t)(i - 1) * 64 * 64;
    const float* bi = brest + (size_t)(i - 1) * 64;
    // neighbor sum
    hipMemsetAsync(nbhw, 0, (size_t)n * 64 * sizeof(float), stream);
    k_spmm<<<spmmBlocks, 256, 0, stream>>>(hbuf, src, dst, nbhw, E);
    // attention gate: v = relu(h@W1a + b1 + (nb*invind)@W1b); a = sigmoid(v@W2+b2); h += a*nbm
    k_gemm<64,0,0,0><<<dim3(nt,1), 256, 0, stream>>>(hbuf, attW1, attb1, nullptr, vbuf, n, 64);
    k_gemm<64,1,1,1><<<dim3(nt,1), 256, 0, stream>>>(nbhw, attW1 + 64 * 64, nullptr, invind, vbuf, n, 64);
    k_attupd<<<cdiv_i(n, 4), 256, 0, stream>>>(vbuf, attW2, attb2, nbhw, invind, hbuf, n);
    // conv: hw = (h*out_norm)@Wi ; agg = scatter(hw) ; h = relu(BN(agg*innorm+bi) + h)
    k_gemm<64,0,0,1><<<dim3(nt,1), 256, 0, stream>>>(hbuf, Wi, nullptr, outnorm, nbhw, n, 64);
    hipMemsetAsync(agg, 0, (size_t)n * 64 * sizeof(float), stream);
    k_spmm<<<spmmBlocks, 256, 0, stream>>>(nbhw, src, dst, agg, E);
    hipMemsetAsync(bnsum, 0, 128 * sizeof(float), stream);
    k_bnstats<<<512, 256, 0, stream>>>(agg, innorm, bi, bnsum, bnsq, n);
    k_bnfin<<<1, 64, 0, stream>>>(bnsum, bnsq, gamma + i * 64, beta + i * 64, bnscale, bnshift, 1.f / (float)n);
    k_post<<<cdiv_i(n * 64, 256), 256, 0, stream>>>(agg, innorm, bi, bnscale, bnshift, hbuf, hbuf, n * 64);
  }

  // ---- classifier ----
  k_gemm<64,0,0,0><<<dim3(nt,1), 256, 0, stream>>>(hbuf, fcW, fcb, nullptr, out, n, 16);
}

// Round 4
// 1736.808 us; speedup vs baseline: 1.9840x; 1.9840x over previous
//
#include <hip/hip_runtime.h>
#include <hip/hip_bf16.h>
#include <math.h>

// EnhancedResGCN forward. N=100000, E=1600000, IN=128, H=64, C=16, L=4.
// Round 3 change: all 7 SpMMs switch from atomic scatter (410 MB write-through
// per SpMM, 70% of runtime) to CSR gather built once per launch.

#define EPS_BN 1e-5f

static inline int cdiv_i(int a, int b){ return (a + b - 1) / b; }

// ---------------- degree count: float out-deg + int in-deg ----------------
__global__ void k_cnt(const int* __restrict__ src, const int* __restrict__ dst,
                      float* __restrict__ outd, int* __restrict__ cnt, int E){
  int e = blockIdx.x * blockDim.x + threadIdx.x;
  if (e < E){
    atomicAdd(&outd[src[e]], 1.f);
    atomicAdd(&cnt[dst[e]], 1);
  }
}

__global__ void k_norm2(float* __restrict__ outn, const int* __restrict__ cnt,
                        float* __restrict__ innorm, float* __restrict__ invind, int n){
  int i = blockIdx.x * blockDim.x + threadIdx.x;
  if (i < n){
    float od = fmaxf(outn[i], 1.f);
    float id = fmaxf((float)cnt[i], 1.f);
    outn[i]   = rsqrtf(od);   // out_norm (in place over outd)
    innorm[i] = rsqrtf(id);   // in_norm
    invind[i] = 1.f / id;     // 1/in_deg (clamped)
  }
}

// ---------------- exclusive scan of cnt[n] -> rowptr[n] (rowptr[n]=E) ----------------
#define SCAN_B 256
__global__ void k_scan_a(const int* __restrict__ cnt, int* __restrict__ bsum, int n){
  __shared__ int sm[SCAN_B];
  int i = blockIdx.x * SCAN_B + threadIdx.x;
  sm[threadIdx.x] = (i < n) ? cnt[i] : 0;
  __syncthreads();
  for (int s = SCAN_B / 2; s; s >>= 1){
    if (threadIdx.x < s) sm[threadIdx.x] += sm[threadIdx.x + s];
    __syncthreads();
  }
  if (threadIdx.x == 0) bsum[blockIdx.x] = sm[0];
}

// single block of 512; nb <= 512 (n=100k -> nb=391)
__global__ void k_scan_b(int* __restrict__ bsum, int nb, int* __restrict__ rowptr_n, int E){
  __shared__ int sm[512];
  int t = threadIdx.x;
  int orig = (t < nb) ? bsum[t] : 0;
  sm[t] = orig;
  __syncthreads();
  for (int off = 1; off < 512; off <<= 1){
    int v = (t >= off) ? sm[t - off] : 0;
    __syncthreads();
    sm[t] += v;
    __syncthreads();
  }
  if (t < nb) bsum[t] = sm[t] - orig;   // exclusive block offsets
  if (t == 0) *rowptr_n = E;
}

__global__ void k_scan_c(const int* __restrict__ cnt, const int* __restrict__ bsum,
                         int* __restrict__ rowptr, int n){
  __shared__ int sm[SCAN_B];
  int i = blockIdx.x * SCAN_B + threadIdx.x;
  int orig = (i < n) ? cnt[i] : 0;
  sm[threadIdx.x] = orig;
  __syncthreads();
  for (int off = 1; off < SCAN_B; off <<= 1){
    int v = (threadIdx.x >= off) ? sm[threadIdx.x - off] : 0;
    __syncthreads();
    sm[threadIdx.x] += v;
    __syncthreads();
  }
  if (i < n) rowptr[i] = sm[threadIdx.x] - orig + bsum[blockIdx.x];
}

__global__ void k_fill(const int* __restrict__ src, const int* __restrict__ dst,
                       const int* __restrict__ rowptr, int* __restrict__ cursor,
                       int* __restrict__ csr, int E){
  int e = blockIdx.x * blockDim.x + threadIdx.x;
  if (e < E){
    int d = dst[e];
    int pos = rowptr[d] + atomicAdd(&cursor[d], 1);
    csr[pos] = src[e];
  }
}

// ---------------- dense GEMM: Y[n,nout] = (RS? X*rscale : X)[n,K] @ W[K,nout] (+bias)(+=Y)(relu) ----
template<int K, int RELU, int ACC, int RS>
__global__ __launch_bounds__(256) void k_gemm(
    const float* __restrict__ X, const float* __restrict__ W,
    const float* __restrict__ bias, const float* __restrict__ rscale,
    float* __restrict__ Y, int n, int nout)
{
  __shared__ __align__(16) float XT[32][68];
  __shared__ __align__(16) float WS[32][64];
  const int tid = threadIdx.x;
  const int tx = tid & 15, ty = tid >> 4;
  const int row0 = blockIdx.x * 64, col0 = blockIdx.y * 64;
  float acc[4][4] = {};
  for (int k0 = 0; k0 < K; k0 += 32){
    __syncthreads();
#pragma unroll
    for (int it = 0; it < 8; ++it){
      int idx = it * 256 + tid;
      int r = idx >> 5, kk = idx & 31;
      int row = row0 + r;
      float v = 0.f;
      if (row < n){
        v = X[(size_t)row * K + (k0 + kk)];
        if (RS) v *= rscale[row];
      }
      XT[kk][r] = v;
    }
#pragma unroll
    for (int it = 0; it < 8; ++it){
      int idx = it * 256 + tid;
      int kk = idx >> 6, c = idx & 63;
      int col = col0 + c;
      WS[kk][c] = (col < nout) ? W[(size_t)(k0 + kk) * nout + col] : 0.f;
    }
    __syncthreads();
#pragma unroll
    for (int kk = 0; kk < 32; ++kk){
      const float4 xv = *reinterpret_cast<const float4*>(&XT[kk][ty * 4]);
      const float4 wv = *reinterpret_cast<const float4*>(&WS[kk][tx * 4]);
      float xa[4] = {xv.x, xv.y, xv.z, xv.w};
      float wa[4] = {wv.x, wv.y, wv.z, wv.w};
#pragma unroll
      for (int i = 0; i < 4; ++i)
#pragma unroll
        for (int j = 0; j < 4; ++j)
          acc[i][j] = fmaf(xa[i], wa[j], acc[i][j]);
    }
  }
#pragma unroll
  for (int i = 0; i < 4; ++i){
    int row = row0 + ty * 4 + i;
    if (row >= n) continue;
#pragma unroll
    for (int j = 0; j < 4; ++j){
      int col = col0 + tx * 4 + j;
      if (col >= nout) continue;
      float v = acc[i][j];
      if (bias) v += bias[col];
      size_t o = (size_t)row * nout + col;
      if (ACC) v += Y[o];
      if (RELU) v = fmaxf(v, 0.f);
      Y[o] = v;
    }
  }
}

// ---------------- CSR gather SpMM: out[d] = sum over in-edges of x[src] ----------------
__global__ void k_gather(const float* __restrict__ x, const int* __restrict__ rowptr,
                         const int* __restrict__ csr, float* __restrict__ out, int n){
  int node = blockIdx.x * 4 + (threadIdx.x >> 6);
  int f = threadIdx.x & 63;
  if (node >= n) return;
  int beg = rowptr[node], end = rowptr[node + 1];
  float a0 = 0.f, a1 = 0.f;
  int e = beg;
  for (; e + 1 < end; e += 2){
    int s0 = csr[e], s1 = csr[e + 1];
    a0 += x[(size_t)s0 * 64 + f];
    a1 += x[(size_t)s1 * 64 + f];
  }
  if (e < end) a0 += x[(size_t)csr[e] * 64 + f];
  out[(size_t)node * 64 + f] = a0 + a1;
}

// ---------------- BatchNorm stats over z = agg*in_norm + b ----------------
__global__ void k_bnstats(const float* __restrict__ agg, const float* __restrict__ innorm,
                          const float* __restrict__ b, float* __restrict__ sum,
                          float* __restrict__ sumsq, int n){
  __shared__ float s1[4][64], s2[4][64];
  int f = threadIdx.x & 63, g = threadIdx.x >> 6;
  float bf = b[f];
  float a1 = 0.f, a2 = 0.f;
  for (int row = blockIdx.x * 4 + g; row < n; row += gridDim.x * 4){
    float z = agg[(size_t)row * 64 + f] * innorm[row] + bf;
    a1 += z; a2 += z * z;
  }
  s1[g][f] = a1; s2[g][f] = a2;
  __syncthreads();
  if (threadIdx.x < 64){
    float t1 = s1[0][f] + s1[1][f] + s1[2][f] + s1[3][f];
    float t2 = s2[0][f] + s2[1][f] + s2[2][f] + s2[3][f];
    atomicAdd(&sum[f], t1);
    atomicAdd(&sumsq[f], t2);
  }
}

__global__ void k_bnfin(const float* __restrict__ sum, const float* __restrict__ sumsq,
                        const float* __restrict__ gamma, const float* __restrict__ beta,
                        float* __restrict__ scale, float* __restrict__ shift, float inv_n){
  int f = threadIdx.x;  // 64 threads
  float mu  = sum[f] * inv_n;
  float var = sumsq[f] * inv_n - mu * mu;
  float sc  = gamma[f] * rsqrtf(var + EPS_BN);
  scale[f] = sc;
  shift[f] = beta[f] - mu * sc;
}

// ---------------- epilogue: h = relu(BN(agg*innorm+b) [+ hres]) ----------------
__global__ void k_post(const float* __restrict__ agg, const float* __restrict__ innorm,
                       const float* __restrict__ b, const float* __restrict__ scale,
                       const float* __restrict__ shift, const float* __restrict__ hres,
                       float* __restrict__ hout, int n64){
  int i = blockIdx.x * blockDim.x + threadIdx.x;
  if (i >= n64) return;
  int f = i & 63, row = i >> 6;
  float z = agg[i] * innorm[row] + b[f];
  z = z * scale[f] + shift[f];
  if (hres) z += hres[i];
  hout[i] = fmaxf(z, 0.f);
}

// ---------------- attention: a = sigmoid(v . W2 + b2); h += a * nb * invind ----------------
__global__ void k_attupd(const float* __restrict__ v, const float* __restrict__ W2,
                         const float* __restrict__ b2, const float* __restrict__ nb,
                         const float* __restrict__ invind, float* __restrict__ h, int n){
  int row = blockIdx.x * 4 + (threadIdx.x >> 6);
  int f = threadIdx.x & 63;
  if (row >= n) return;
  float s = v[(size_t)row * 64 + f] * W2[f];
#pragma unroll
  for (int off = 32; off; off >>= 1) s += __shfl_xor(s, off);
  float a = 1.f / (1.f + expf(-(s + b2[0])));
  size_t o = (size_t)row * 64 + f;
  float nbm = nb[o] * invind[row];
  h[o] += a * nbm;
}

extern "C" void kernel_launch(void* const* d_in, const int* in_sizes, int n_in,
                              void* d_out, int out_size, void* d_ws, size_t ws_size,
                              hipStream_t stream) {
  const float* features = (const float*)d_in[0];
  const int*   src      = (const int*)d_in[1];
  const int*   dst      = (const int*)d_in[2];
  const float* encW1 = (const float*)d_in[3];  const float* encb1 = (const float*)d_in[4];
  const float* encW2 = (const float*)d_in[5];  const float* encb2 = (const float*)d_in[6];
  const float* encW3 = (const float*)d_in[7];  const float* encb3 = (const float*)d_in[8];
  const float* attW1 = (const float*)d_in[9];  const float* attb1 = (const float*)d_in[10];
  const float* attW2 = (const float*)d_in[11]; const float* attb2 = (const float*)d_in[12];
  const float* W0    = (const float*)d_in[13]; const float* b0    = (const float*)d_in[14];
  const float* Wrest = (const float*)d_in[15]; const float* brest = (const float*)d_in[16];
  const float* gamma = (const float*)d_in[17]; const float* beta  = (const float*)d_in[18];
  const float* fcW   = (const float*)d_in[19]; const float* fcb   = (const float*)d_in[20];
  float* out = (float*)d_out;

  const int n = in_sizes[0] / 128;   // 100000
  const int E = in_sizes[1];         // 1600000

  // float workspace
  float* ws      = (float*)d_ws;
  float* h128    = ws;
  float* agg     = h128;                       // alias: h128 dead after layer-0 GEMM
  float* vbuf    = h128;                       // alias
  float* hbuf    = h128 + (size_t)n * 128;
  float* nbhw    = hbuf + (size_t)n * 64;
  float* outnorm = nbhw + (size_t)n * 64;      // also outd during counting
  float* innorm  = outnorm + n;
  float* invind  = innorm + n;
  float* bnsum   = invind + n;
  float* bnsq    = bnsum + 64;
  float* bnscale = bnsq + 64;
  float* bnshift = bnscale + 64;
  // int workspace (CSR)
  int* cnt    = (int*)(bnshift + 64);          // reused as cursor for k_fill
  int* rowptr = cnt + n;                       // n+1
  int* csr    = rowptr + n + 1;                // E
  int* bsum   = csr + E;                       // 512

  const int nt = cdiv_i(n, 64);
  const int nb = cdiv_i(n, SCAN_B);            // 391 scan blocks

  // ---- degrees, norms, CSR build ----
  hipMemsetAsync(outnorm, 0, (size_t)n * sizeof(float), stream);
  hipMemsetAsync(cnt, 0, (size_t)n * sizeof(int), stream);
  k_cnt<<<cdiv_i(E, 256), 256, 0, stream>>>(src, dst, outnorm, cnt, E);
  k_scan_a<<<nb, SCAN_B, 0, stream>>>(cnt, bsum, n);
  k_scan_b<<<1, 512, 0, stream>>>(bsum, nb, rowptr + n, E);
  k_scan_c<<<nb, SCAN_B, 0, stream>>>(cnt, bsum, rowptr, n);
  k_norm2<<<cdiv_i(n, 256), 256, 0, stream>>>(outnorm, cnt, innorm, invind, n);
  hipMemsetAsync(cnt, 0, (size_t)n * sizeof(int), stream);   // cnt -> cursor
  k_fill<<<cdiv_i(E, 256), 256, 0, stream>>>(src, dst, rowptr, cnt, csr, E);

  // ---- encoder MLP ----
  k_gemm<128,1,0,0><<<dim3(nt,1), 256, 0, stream>>>(features, encW1, encb1, nullptr, hbuf, n, 64);
  k_gemm<64, 1,0,0><<<dim3(nt,1), 256, 0, stream>>>(hbuf, encW2, encb2, nullptr, nbhw, n, 32);
  k_gemm<32, 0,0,0><<<dim3(nt,2), 256, 0, stream>>>(nbhw, encW3, encb3, nullptr, h128, n, 128);

  // ---- layer 0: conv on h128 ----
  k_gemm<128,0,0,1><<<dim3(nt,1), 256, 0, stream>>>(h128, W0, nullptr, outnorm, nbhw, n, 64);
  k_gather<<<cdiv_i(n, 4), 256, 0, stream>>>(nbhw, rowptr, csr, agg, n);
  hipMemsetAsync(bnsum, 0, 128 * sizeof(float), stream);
  k_bnstats<<<512, 256, 0, stream>>>(agg, innorm, b0, bnsum, bnsq, n);
  k_bnfin<<<1, 64, 0, stream>>>(bnsum, bnsq, gamma, beta, bnscale, bnshift, 1.f / (float)n);
  k_post<<<cdiv_i(n * 64, 256), 256, 0, stream>>>(agg, innorm, b0, bnscale, bnshift, nullptr, hbuf, n * 64);

  // ---- layers 1..3 ----
  for (int i = 1; i < 4; ++i){
    const float* Wi = Wrest + (size_t)(i - 1) * 64 * 64;
    const float* bi = brest + (size_t)(i - 1) * 64;
    // neighbor sum (nb = gather of h)
    k_gather<<<cdiv_i(n, 4), 256, 0, stream>>>(hbuf, rowptr, csr, nbhw, n);
    // attention gate: v = relu(h@W1a + b1 + (nb*invind)@W1b); a = sigmoid(v@W2+b2); h += a*nbm
    k_gemm<64,0,0,0><<<dim3(nt,1), 256, 0, stream>>>(hbuf, attW1, attb1, nullptr, vbuf, n, 64);
    k_gemm<64,1,1,1><<<dim3(nt,1), 256, 0, stream>>>(nbhw, attW1 + 64 * 64, nullptr, invind, vbuf, n, 64);
    k_attupd<<<cdiv_i(n, 4), 256, 0, stream>>>(vbuf, attW2, attb2, nbhw, invind, hbuf, n);
    // conv: hw = (h*out_norm)@Wi ; agg = gather(hw) ; h = relu(BN(agg*innorm+bi) + h)
    k_gemm<64,0,0,1><<<dim3(nt,1), 256, 0, stream>>>(hbuf, Wi, nullptr, outnorm, nbhw, n, 64);
    k_gather<<<cdiv_i(n, 4), 256, 0, stream>>>(nbhw, rowptr, csr, agg, n);
    hipMemsetAsync(bnsum, 0, 128 * sizeof(float), stream);
    k_bnstats<<<512, 256, 0, stream>>>(agg, innorm, bi, bnsum, bnsq, n);
    k_bnfin<<<1, 64, 0, stream>>>(bnsum, bnsq, gamma + i * 64, beta + i * 64, bnscale, bnshift, 1.f / (float)n);
    k_post<<<cdiv_i(n * 64, 256), 256, 0, stream>>>(agg, innorm, bi, bnscale, bnshift, hbuf, hbuf, n * 64);
  }

  // ---- classifier ----
  k_gemm<64,0,0,0><<<dim3(nt,1), 256, 0, stream>>>(hbuf, fcW, fcb, nullptr, out, n, 16);
}

// Round 6
// 1344.579 us; speedup vs baseline: 2.5628x; 1.2917x over previous
//
#include <hip/hip_runtime.h>
#include <hip/hip_bf16.h>
#include <math.h>

// EnhancedResGCN forward. N=100000, E=1600000, IN=128, H=64, C=16, L=4.
// Round 4 change (resubmit; infra failure): all dense GEMMs -> bf16 MFMA
// (16x16x32), fp32 buffers, A streamed from global, W prepacked to LDS.

#define EPS_BN 1e-5f

static inline int cdiv_i(int a, int b){ return (a + b - 1) / b; }

typedef __attribute__((ext_vector_type(8))) short bf16x8;
typedef __attribute__((ext_vector_type(4))) float f32x4;

__device__ inline short f2bf(float f){
  unsigned int u = __builtin_bit_cast(unsigned int, f);
  u += 0x7FFFu + ((u >> 16) & 1u);          // round-to-nearest-even
  return (short)(u >> 16);
}

// ---------------- degree count: float out-deg + int in-deg ----------------
__global__ void k_cnt(const int* __restrict__ src, const int* __restrict__ dst,
                      float* __restrict__ outd, int* __restrict__ cnt, int E){
  int e = blockIdx.x * blockDim.x + threadIdx.x;
  if (e < E){
    atomicAdd(&outd[src[e]], 1.f);
    atomicAdd(&cnt[dst[e]], 1);
  }
}

__global__ void k_norm2(float* __restrict__ outn, const int* __restrict__ cnt,
                        float* __restrict__ innorm, float* __restrict__ invind, int n){
  int i = blockIdx.x * blockDim.x + threadIdx.x;
  if (i < n){
    float od = fmaxf(outn[i], 1.f);
    float id = fmaxf((float)cnt[i], 1.f);
    outn[i]   = rsqrtf(od);
    innorm[i] = rsqrtf(id);
    invind[i] = 1.f / id;
  }
}

// ---------------- exclusive scan of cnt[n] -> rowptr ----------------
#define SCAN_B 256
__global__ void k_scan_a(const int* __restrict__ cnt, int* __restrict__ bsum, int n){
  __shared__ int sm[SCAN_B];
  int i = blockIdx.x * SCAN_B + threadIdx.x;
  sm[threadIdx.x] = (i < n) ? cnt[i] : 0;
  __syncthreads();
  for (int s = SCAN_B / 2; s; s >>= 1){
    if (threadIdx.x < s) sm[threadIdx.x] += sm[threadIdx.x + s];
    __syncthreads();
  }
  if (threadIdx.x == 0) bsum[blockIdx.x] = sm[0];
}

__global__ void k_scan_b(int* __restrict__ bsum, int nb, int* __restrict__ rowptr_n, int E){
  __shared__ int sm[512];
  int t = threadIdx.x;
  int orig = (t < nb) ? bsum[t] : 0;
  sm[t] = orig;
  __syncthreads();
  for (int off = 1; off < 512; off <<= 1){
    int v = (t >= off) ? sm[t - off] : 0;
    __syncthreads();
    sm[t] += v;
    __syncthreads();
  }
  if (t < nb) bsum[t] = sm[t] - orig;
  if (t == 0) *rowptr_n = E;
}

__global__ void k_scan_c(const int* __restrict__ cnt, const int* __restrict__ bsum,
                         int* __restrict__ rowptr, int n){
  __shared__ int sm[SCAN_B];
  int i = blockIdx.x * SCAN_B + threadIdx.x;
  int orig = (i < n) ? cnt[i] : 0;
  sm[threadIdx.x] = orig;
  __syncthreads();
  for (int off = 1; off < SCAN_B; off <<= 1){
    int v = (threadIdx.x >= off) ? sm[threadIdx.x - off] : 0;
    __syncthreads();
    sm[threadIdx.x] += v;
    __syncthreads();
  }
  if (i < n) rowptr[i] = sm[threadIdx.x] - orig + bsum[blockIdx.x];
}

__global__ void k_fill(const int* __restrict__ src, const int* __restrict__ dst,
                       const int* __restrict__ rowptr, int* __restrict__ cursor,
                       int* __restrict__ csr, int E){
  int e = blockIdx.x * blockDim.x + threadIdx.x;
  if (e < E){
    int d = dst[e];
    int pos = rowptr[d] + atomicAdd(&cursor[d], 1);
    csr[pos] = src[e];
  }
}

// ---------------- MFMA GEMM: Y[n,nout] = (RS? X*rscale : X) @ W (+bias)(+=Y)(relu) ----
// Block: 256 thr = 4 waves; each wave 16 rows x NF*16 cols; block = 64 rows.
// A streamed from global (lane: 8 consecutive fp32 -> bf16), W prepacked in LDS.
template<int K, int NF, int RELU, int ACC, int RS>
__global__ __launch_bounds__(256) void k_gemm_mfma(
    const float* __restrict__ X, const float* __restrict__ W,
    const float* __restrict__ bias, const float* __restrict__ rscale,
    float* __restrict__ Y, int n, int nout)
{
  constexpr int KSTEPS = K / 32;
  __shared__ short WP[KSTEPS * NF * 4 * 16 * 8];   // fragment-ordered bf16 W

  const int tid  = threadIdx.x;
  const int wave = tid >> 6, lane = tid & 63;
  const int lrow = lane & 15, lgrp = lane >> 4;    // A row-in-frag / k-group
  const int col0 = blockIdx.y * (NF * 16);

  // ---- prepack W into LDS fragments ----
  for (int i = tid; i < KSTEPS * NF * 4 * 16; i += 256){
    int c  = i & 15;
    int kg = (i >> 4) & 3;
    int t2 = i >> 6;
    int nf = t2 % NF, kstep = t2 / NF;
    int col = col0 + nf * 16 + c;
    short* dst8 = &WP[((kstep * NF + nf) * 4 + kg) * 128 + c * 8];
#pragma unroll
    for (int j = 0; j < 8; ++j){
      int k = kstep * 32 + kg * 8 + j;
      dst8[j] = (col < nout) ? f2bf(W[(size_t)k * nout + col]) : (short)0;
    }
  }
  __syncthreads();

  const int row = blockIdx.x * 64 + wave * 16 + lrow;  // this lane's A row
  const bool rok = (row < n);
  const float rs = (RS && rok) ? rscale[row] : 1.f;

  f32x4 acc[NF];
#pragma unroll
  for (int nf = 0; nf < NF; ++nf) acc[nf] = (f32x4){0.f, 0.f, 0.f, 0.f};

#pragma unroll
  for (int kstep = 0; kstep < KSTEPS; ++kstep){
    bf16x8 a;
    if (rok){
      const float* p = X + (size_t)row * K + kstep * 32 + lgrp * 8;
      float4 v0 = *reinterpret_cast<const float4*>(p);
      float4 v1 = *reinterpret_cast<const float4*>(p + 4);
      a[0] = f2bf(v0.x * rs); a[1] = f2bf(v0.y * rs);
      a[2] = f2bf(v0.z * rs); a[3] = f2bf(v0.w * rs);
      a[4] = f2bf(v1.x * rs); a[5] = f2bf(v1.y * rs);
      a[6] = f2bf(v1.z * rs); a[7] = f2bf(v1.w * rs);
    } else {
#pragma unroll
      for (int j = 0; j < 8; ++j) a[j] = 0;
    }
#pragma unroll
    for (int nf = 0; nf < NF; ++nf){
      bf16x8 b = *reinterpret_cast<const bf16x8*>(
          &WP[((kstep * NF + nf) * 4 + lgrp) * 128 + lrow * 8]);
      acc[nf] = __builtin_amdgcn_mfma_f32_16x16x32_bf16(a, b, acc[nf], 0, 0, 0);
    }
  }

  // ---- epilogue: D frag row=(lane>>4)*4+r, col=lane&15 ----
#pragma unroll
  for (int nf = 0; nf < NF; ++nf){
    int col = col0 + nf * 16 + lrow;
    if (col >= nout) continue;
    float bv = bias ? bias[col] : 0.f;
#pragma unroll
    for (int r = 0; r < 4; ++r){
      int orow = blockIdx.x * 64 + wave * 16 + lgrp * 4 + r;
      if (orow >= n) continue;
      float v = acc[nf][r] + bv;
      size_t o = (size_t)orow * nout + col;
      if (ACC) v += Y[o];
      if (RELU) v = fmaxf(v, 0.f);
      Y[o] = v;
    }
  }
}

// ---------------- CSR gather SpMM: out[d] = sum over in-edges of x[src] ----------------
__global__ void k_gather(const float* __restrict__ x, const int* __restrict__ rowptr,
                         const int* __restrict__ csr, float* __restrict__ out, int n){
  int node = blockIdx.x * 4 + (threadIdx.x >> 6);
  int f = threadIdx.x & 63;
  if (node >= n) return;
  int beg = rowptr[node], end = rowptr[node + 1];
  float a0 = 0.f, a1 = 0.f;
  int e = beg;
  for (; e + 1 < end; e += 2){
    int s0 = csr[e], s1 = csr[e + 1];
    a0 += x[(size_t)s0 * 64 + f];
    a1 += x[(size_t)s1 * 64 + f];
  }
  if (e < end) a0 += x[(size_t)csr[e] * 64 + f];
  out[(size_t)node * 64 + f] = a0 + a1;
}

// ---------------- BatchNorm stats over z = agg*in_norm + b ----------------
__global__ void k_bnstats(const float* __restrict__ agg, const float* __restrict__ innorm,
                          const float* __restrict__ b, float* __restrict__ sum,
                          float* __restrict__ sumsq, int n){
  __shared__ float s1[4][64], s2[4][64];
  int f = threadIdx.x & 63, g = threadIdx.x >> 6;
  float bf = b[f];
  float a1 = 0.f, a2 = 0.f;
  for (int row = blockIdx.x * 4 + g; row < n; row += gridDim.x * 4){
    float z = agg[(size_t)row * 64 + f] * innorm[row] + bf;
    a1 += z; a2 += z * z;
  }
  s1[g][f] = a1; s2[g][f] = a2;
  __syncthreads();
  if (threadIdx.x < 64){
    float t1 = s1[0][f] + s1[1][f] + s1[2][f] + s1[3][f];
    float t2 = s2[0][f] + s2[1][f] + s2[2][f] + s2[3][f];
    atomicAdd(&sum[f], t1);
    atomicAdd(&sumsq[f], t2);
  }
}

__global__ void k_bnfin(const float* __restrict__ sum, const float* __restrict__ sumsq,
                        const float* __restrict__ gamma, const float* __restrict__ beta,
                        float* __restrict__ scale, float* __restrict__ shift, float inv_n){
  int f = threadIdx.x;  // 64 threads
  float mu  = sum[f] * inv_n;
  float var = sumsq[f] * inv_n - mu * mu;
  float sc  = gamma[f] * rsqrtf(var + EPS_BN);
  scale[f] = sc;
  shift[f] = beta[f] - mu * sc;
}

// ---------------- epilogue: h = relu(BN(agg*innorm+b) [+ hres]) ----------------
__global__ void k_post(const float* __restrict__ agg, const float* __restrict__ innorm,
                       const float* __restrict__ b, const float* __restrict__ scale,
                       const float* __restrict__ shift, const float* __restrict__ hres,
                       float* __restrict__ hout, int n64){
  int i = blockIdx.x * blockDim.x + threadIdx.x;
  if (i >= n64) return;
  int f = i & 63, row = i >> 6;
  float z = agg[i] * innorm[row] + b[f];
  z = z * scale[f] + shift[f];
  if (hres) z += hres[i];
  hout[i] = fmaxf(z, 0.f);
}

// ---------------- attention: a = sigmoid(v . W2 + b2); h += a * nb * invind ----------------
__global__ void k_attupd(const float* __restrict__ v, const float* __restrict__ W2,
                         const float* __restrict__ b2, const float* __restrict__ nb,
                         const float* __restrict__ invind, float* __restrict__ h, int n){
  int row = blockIdx.x * 4 + (threadIdx.x >> 6);
  int f = threadIdx.x & 63;
  if (row >= n) return;
  float s = v[(size_t)row * 64 + f] * W2[f];
#pragma unroll
  for (int off = 32; off; off >>= 1) s += __shfl_xor(s, off);
  float a = 1.f / (1.f + expf(-(s + b2[0])));
  size_t o = (size_t)row * 64 + f;
  float nbm = nb[o] * invind[row];
  h[o] += a * nbm;
}

extern "C" void kernel_launch(void* const* d_in, const int* in_sizes, int n_in,
                              void* d_out, int out_size, void* d_ws, size_t ws_size,
                              hipStream_t stream) {
  const float* features = (const float*)d_in[0];
  const int*   src      = (const int*)d_in[1];
  const int*   dst      = (const int*)d_in[2];
  const float* encW1 = (const float*)d_in[3];  const float* encb1 = (const float*)d_in[4];
  const float* encW2 = (const float*)d_in[5];  const float* encb2 = (const float*)d_in[6];
  const float* encW3 = (const float*)d_in[7];  const float* encb3 = (const float*)d_in[8];
  const float* attW1 = (const float*)d_in[9];  const float* attb1 = (const float*)d_in[10];
  const float* attW2 = (const float*)d_in[11]; const float* attb2 = (const float*)d_in[12];
  const float* W0    = (const float*)d_in[13]; const float* b0    = (const float*)d_in[14];
  const float* Wrest = (const float*)d_in[15]; const float* brest = (const float*)d_in[16];
  const float* gamma = (const float*)d_in[17]; const float* beta  = (const float*)d_in[18];
  const float* fcW   = (const float*)d_in[19]; const float* fcb   = (const float*)d_in[20];
  float* out = (float*)d_out;

  const int n = in_sizes[0] / 128;   // 100000
  const int E = in_sizes[1];         // 1600000

  // float workspace
  float* ws      = (float*)d_ws;
  float* h128    = ws;
  float* agg     = h128;                       // alias: h128 dead after layer-0 GEMM
  float* vbuf    = h128;                       // alias
  float* hbuf    = h128 + (size_t)n * 128;
  float* nbhw    = hbuf + (size_t)n * 64;
  float* outnorm = nbhw + (size_t)n * 64;      // also outd during counting
  float* innorm  = outnorm + n;
  float* invind  = innorm + n;
  float* bnsum   = invind + n;
  float* bnsq    = bnsum + 64;
  float* bnscale = bnsq + 64;
  float* bnshift = bnscale + 64;
  // int workspace (CSR)
  int* cnt    = (int*)(bnshift + 64);          // reused as cursor for k_fill
  int* rowptr = cnt + n;                       // n+1
  int* csr    = rowptr + n + 1;                // E
  int* bsum   = csr + E;                       // 512

  const int nt = cdiv_i(n, 64);
  const int nb = cdiv_i(n, SCAN_B);

  // ---- degrees, norms, CSR build ----
  hipMemsetAsync(outnorm, 0, (size_t)n * sizeof(float), stream);
  hipMemsetAsync(cnt, 0, (size_t)n * sizeof(int), stream);
  k_cnt<<<cdiv_i(E, 256), 256, 0, stream>>>(src, dst, outnorm, cnt, E);
  k_scan_a<<<nb, SCAN_B, 0, stream>>>(cnt, bsum, n);
  k_scan_b<<<1, 512, 0, stream>>>(bsum, nb, rowptr + n, E);
  k_scan_c<<<nb, SCAN_B, 0, stream>>>(cnt, bsum, rowptr, n);
  k_norm2<<<cdiv_i(n, 256), 256, 0, stream>>>(outnorm, cnt, innorm, invind, n);
  hipMemsetAsync(cnt, 0, (size_t)n * sizeof(int), stream);   // cnt -> cursor
  k_fill<<<cdiv_i(E, 256), 256, 0, stream>>>(src, dst, rowptr, cnt, csr, E);

  // ---- encoder MLP ----
  k_gemm_mfma<128,4,1,0,0><<<dim3(nt,1), 256, 0, stream>>>(features, encW1, encb1, nullptr, hbuf, n, 64);
  k_gemm_mfma<64, 2,1,0,0><<<dim3(nt,1), 256, 0, stream>>>(hbuf, encW2, encb2, nullptr, nbhw, n, 32);
  k_gemm_mfma<32, 4,0,0,0><<<dim3(nt,2), 256, 0, stream>>>(nbhw, encW3, encb3, nullptr, h128, n, 128);

  // ---- layer 0: conv on h128 ----
  k_gemm_mfma<128,4,0,0,1><<<dim3(nt,1), 256, 0, stream>>>(h128, W0, nullptr, outnorm, nbhw, n, 64);
  k_gather<<<cdiv_i(n, 4), 256, 0, stream>>>(nbhw, rowptr, csr, agg, n);
  hipMemsetAsync(bnsum, 0, 128 * sizeof(float), stream);
  k_bnstats<<<512, 256, 0, stream>>>(agg, innorm, b0, bnsum, bnsq, n);
  k_bnfin<<<1, 64, 0, stream>>>(bnsum, bnsq, gamma, beta, bnscale, bnshift, 1.f / (float)n);
  k_post<<<cdiv_i(n * 64, 256), 256, 0, stream>>>(agg, innorm, b0, bnscale, bnshift, nullptr, hbuf, n * 64);

  // ---- layers 1..3 ----
  for (int i = 1; i < 4; ++i){
    const float* Wi = Wrest + (size_t)(i - 1) * 64 * 64;
    const float* bi = brest + (size_t)(i - 1) * 64;
    // neighbor sum (nb = gather of h)
    k_gather<<<cdiv_i(n, 4), 256, 0, stream>>>(hbuf, rowptr, csr, nbhw, n);
    // attention gate: v = relu(h@W1a + b1 + (nb*invind)@W1b); a = sigmoid(v@W2+b2); h += a*nbm
    k_gemm_mfma<64,4,0,0,0><<<dim3(nt,1), 256, 0, stream>>>(hbuf, attW1, attb1, nullptr, vbuf, n, 64);
    k_gemm_mfma<64,4,1,1,1><<<dim3(nt,1), 256, 0, stream>>>(nbhw, attW1 + 64 * 64, nullptr, invind, vbuf, n, 64);
    k_attupd<<<cdiv_i(n, 4), 256, 0, stream>>>(vbuf, attW2, attb2, nbhw, invind, hbuf, n);
    // conv: hw = (h*out_norm)@Wi ; agg = gather(hw) ; h = relu(BN(agg*innorm+bi) + h)
    k_gemm_mfma<64,4,0,0,1><<<dim3(nt,1), 256, 0, stream>>>(hbuf, Wi, nullptr, outnorm, nbhw, n, 64);
    k_gather<<<cdiv_i(n, 4), 256, 0, stream>>>(nbhw, rowptr, csr, agg, n);
    hipMemsetAsync(bnsum, 0, 128 * sizeof(float), stream);
    k_bnstats<<<512, 256, 0, stream>>>(agg, innorm, bi, bnsum, bnsq, n);
    k_bnfin<<<1, 64, 0, stream>>>(bnsum, bnsq, gamma + i * 64, beta + i * 64, bnscale, bnshift, 1.f / (float)n);
    k_post<<<cdiv_i(n * 64, 256), 256, 0, stream>>>(agg, innorm, bi, bnscale, bnshift, hbuf, hbuf, n * 64);
  }

  // ---- classifier ----
  k_gemm_mfma<64,1,0,0,0><<<dim3(nt,1), 256, 0, stream>>>(hbuf, fcW, fcb, nullptr, out, n, 16);
}